// Round 9
// baseline (130.142 us; speedup 1.0000x reference)
//
#include <hip/hip_runtime.h>
#include <hip/hip_bf16.h>
#include <math.h>

#define NB 2
#define NN 4096
#define FIN 128
#define FOUT 64
#define LALPHA 0.2f

// ws float-offsets
#define WS_S1    0                          // NB*NN floats (pre-scaled by log2e)
#define WS_S2    (NB*NN)                    // NB*NN floats (pre-scaled by log2e)
#define WS_WHT   (2*NB*NN)                  // NB*FOUT*NN bf16, tile-major layout
#define WS_ABITS (WS_WHT + NB*FOUT*NN/2)    // NN*(NN/32) uint32 = 2 MiB

// whT tile-major layout: element (b, f, j) lives at
//   (b*(NN/32) + (j>>5)) * 2048 + f*32 + (j&31)

typedef __attribute__((ext_vector_type(8))) short short8;
typedef __attribute__((ext_vector_type(4))) float f32x4;

static __device__ inline unsigned int pack2bf(float x, float y) {
    float2 f2; f2.x = x; f2.y = y;
    __hip_bfloat162 pp = __float22bfloat162_rn(f2);
    return *reinterpret_cast<unsigned int*>(&pp);
}

// async global->LDS, 16B per lane (used only for the s2 prologue stage)
#define GLL16(gsrc, ldst)                                                        \
    __builtin_amdgcn_global_load_lds(                                            \
        (const __attribute__((address_space(1))) void*)(gsrc),                   \
        (__attribute__((address_space(3))) void*)(ldst), 16, 0, 0)

// K1: Wh = h@W ; s1 = log2e*(Wh@a1) ; s2 = log2e*(Wh@a2) ; WhT bf16 tile-major.
// At its HBM roofline (~8 us, 64 MiB adj stream) — do not touch.
__global__ __launch_bounds__(256) void k1_proj(const float* __restrict__ h,
                                               const float* __restrict__ W,
                                               const float* __restrict__ a,
                                               const int* __restrict__ adj,
                                               float* __restrict__ ws) {
    __shared__ __align__(16) float hbuf[4][128];
    __shared__ float tbuf[4][68];
    int gid  = blockIdx.x * 256 + threadIdx.x;
    int wid  = gid >> 6;            // 0 .. NB*NN-1
    int lane = threadIdx.x & 63;
    int w    = threadIdx.x >> 6;

    // ---- adj pack: coalesced loads issued early ----
    int prow = 2 * blockIdx.x + (w >> 1);
    const int4* psrc = (const int4*)(adj + (size_t)prow * NN + (w & 1) * 2048);
    int4 pv[8];
#pragma unroll
    for (int k = 0; k < 8; ++k) pv[k] = psrc[k * 64 + lane];

    // ---- stage h row (wave-private), then broadcast-read f32x4 ----
    const float* hrow = h + (size_t)wid * FIN;
    hbuf[w][lane]      = hrow[lane];
    hbuf[w][64 + lane] = hrow[64 + lane];

    float acc = 0.f;
#pragma unroll
    for (int f4 = 0; f4 < 32; ++f4) {
        float4 hv = *(const float4*)&hbuf[w][f4 * 4];
        acc = fmaf(hv.x, W[(f4 * 4 + 0) * FOUT + lane], acc);
        acc = fmaf(hv.y, W[(f4 * 4 + 1) * FOUT + lane], acc);
        acc = fmaf(hv.z, W[(f4 * 4 + 2) * FOUT + lane], acc);
        acc = fmaf(hv.w, W[(f4 * 4 + 3) * FOUT + lane], acc);
    }
    tbuf[w][lane] = acc;
    float v1 = acc * a[lane];
    float v2 = acc * a[FOUT + lane];
#pragma unroll
    for (int off = 32; off; off >>= 1) {
        v1 += __shfl_xor(v1, off);
        v2 += __shfl_xor(v2, off);
    }
    if (lane == 0) {
        ws[WS_S1 + wid] = v1 * 1.44269504088896f;   // pre-scale for exp2 in k3
        ws[WS_S2 + wid] = v2 * 1.44269504088896f;
    }

    // ---- finish adj pack: nibble -> word via 3x shfl_xor OR ----
    unsigned int* ab = (unsigned int*)(ws + WS_ABITS);
#pragma unroll
    for (int k = 0; k < 8; ++k) {
        unsigned int nib = (pv[k].x != 0 ? 1u : 0u)
                         | (pv[k].y != 0 ? 2u : 0u)
                         | (pv[k].z != 0 ? 4u : 0u)
                         | (pv[k].w != 0 ? 8u : 0u);
        unsigned int val = nib << ((lane & 7) * 4);
        val |= __shfl_xor(val, 1);
        val |= __shfl_xor(val, 2);
        val |= __shfl_xor(val, 4);
        if ((lane & 7) == 0)
            ab[(size_t)prow * 128 + (w & 1) * 64 + k * 8 + (lane >> 3)] = val;
    }

    __syncthreads();
    // transpose 4 rows x 64 f -> tile-major whT
    if (threadIdx.x < 64) {
        int f = threadIdx.x;
        int wid0 = blockIdx.x * 4;
        int b  = wid0 >> 12;         // wid0 / NN
        int n0 = wid0 & (NN - 1);
        unsigned short* whT = (unsigned short*)(ws + WS_WHT);
        uint2 pk;
        pk.x = pack2bf(tbuf[0][f], tbuf[1][f]);
        pk.y = pack2bf(tbuf[2][f], tbuf[3][f]);
        size_t off = ((size_t)(b * 128 + (n0 >> 5)) * 2048) + f * 32 + (n0 & 31);
        *(uint2*)&whT[off] = pk;
    }
}

// K3: fused masked softmax + P@Wh via MFMA + flat in-block reduction + ELU.
// Grid = 256 blocks, rt = bid & 127, b = bid >> 7 (r8-proven mapping).
// ABLATION vs r8: whT fragments via a REGISTER pipeline (bfp[2][4], plain
// coalesced 1KB wave-loads from tile-major whT, prefetch distance 2) instead
// of global_load_lds + LDS round-trip. Compiler-tracked vmcnt; no inline-asm
// waits in the loop. s2 LDS stage, ones-MFMA denominator, epilogue unchanged.
__global__ __launch_bounds__(1024, 4) void k3_attn(const float* __restrict__ ws,
                                                   float* __restrict__ out) {
    __shared__ float redbuf[16 * 2048];   // 128 KiB: epilogue partials
    __shared__ float s2buf[16][256];      // 16 KiB: per-wave s2 slice
    __shared__ float lred[16][32];        // 2 KiB: l partials (g*16+row)
    const int tid  = threadIdx.x;
    const int w    = tid >> 6;                   // wave id = j-chunk 0..15
    const int lane = tid & 63;
    const int col  = lane & 15;
    const int quad = lane >> 4;
    const int rt   = blockIdx.x & 127;           // 32-row tile 0..127
    const int b    = blockIdx.x >> 7;            // batch
    const int i0   = rt * 32;
    const int jbase = w * 256;

    const float* __restrict__ s1 = ws + WS_S1 + b * NN;
    const float* __restrict__ s2 = ws + WS_S2 + b * NN;
    const unsigned short* __restrict__ whT =
        (const unsigned short*)(ws + WS_WHT) + (size_t)b * FOUT * NN;
    const unsigned int* __restrict__ abits = (const unsigned int*)(ws + WS_ABITS);

    float* s2s = s2buf[w];
    const unsigned short* wsrc = whT + (size_t)w * 8 * 2048;  // tile (w*8+ks) @ +ks*2048
    const int lsrc = col * 32 + quad * 8;             // per-lane fragment offset (shorts)

    // ---- prologue: masks + s1a + s2 stage, then drain s2's GLL ----
    unsigned int mrow[2][8];
#pragma unroll
    for (int g = 0; g < 2; ++g) {
        const int4* mp = (const int4*)&abits[(size_t)(i0 + g * 16 + col) * 128 + w * 8];
        *(int4*)&mrow[g][0] = mp[0];
        *(int4*)&mrow[g][4] = mp[1];
    }
    float s1a[2];
#pragma unroll
    for (int g = 0; g < 2; ++g) s1a[g] = s1[i0 + g * 16 + col];
    GLL16(&s2[jbase] + lane * 4, s2s);
    asm volatile("s_waitcnt vmcnt(0)" ::: "memory");   // s2s + masks landed

    // ---- register pipeline for bf fragments, prefetch distance 2 ----
    short8 bfp[2][4];
#define LOADTILE(t, ks)                                                    \
    do {                                                                   \
        const unsigned short* wb_ = wsrc + (size_t)(ks) * 2048 + lsrc;     \
        bfp[t][0] = *(const short8*)(wb_ + 0 * 512);                       \
        bfp[t][1] = *(const short8*)(wb_ + 1 * 512);                       \
        bfp[t][2] = *(const short8*)(wb_ + 2 * 512);                       \
        bfp[t][3] = *(const short8*)(wb_ + 3 * 512);                       \
    } while (0)

    LOADTILE(0, 0);
    LOADTILE(1, 1);

    // all-ones bf16 B-fragment for denominator row-sum MFMA
    unsigned int onew[4] = {0x3F803F80u, 0x3F803F80u, 0x3F803F80u, 0x3F803F80u};
    const short8 ones = *(short8*)onew;

    f32x4 acc[2][4];          // [group][nt] numerator
    f32x4 accl[2];            // [group] denominator row-sums
#pragma unroll
    for (int g = 0; g < 2; ++g) {
        accl[g] = (f32x4)0.f;
#pragma unroll
        for (int nt = 0; nt < 4; ++nt) acc[g][nt] = (f32x4)0.f;
    }

#pragma unroll
    for (int ks = 0; ks < 8; ++ks) {
        const int t = ks & 1;

        // ---- p/exp chain from LDS s2 ----
        float4 s2lo = *(const float4*)&s2s[ks * 32 + quad * 8];
        float4 s2hi = *(const float4*)&s2s[ks * 32 + quad * 8 + 4];
        float sj[8] = {s2lo.x, s2lo.y, s2lo.z, s2lo.w,
                       s2hi.x, s2hi.y, s2hi.z, s2hi.w};
        short8 afrag[2];
#pragma unroll
        for (int g = 0; g < 2; ++g) {
            const unsigned int mb = (mrow[g][ks] >> (quad * 8)) & 0xffu;
            float p[8];
#pragma unroll
            for (int jj = 0; jj < 8; ++jj) {
                float e = s1a[g] + sj[jj];
                e = fmaxf(e, LALPHA * e);              // leakyrelu
                float pe = exp2f(e);                   // inputs pre-scaled by log2e
                p[jj] = ((mb >> jj) & 1u) ? pe : 0.f;  // mask
            }
            unsigned int pk[4];
#pragma unroll
            for (int q = 0; q < 4; ++q) pk[q] = pack2bf(p[2 * q], p[2 * q + 1]);
            afrag[g] = *(short8*)pk;
        }

        __builtin_amdgcn_s_setprio(1);
#pragma unroll
        for (int nt = 0; nt < 4; ++nt) {
            acc[0][nt] = __builtin_amdgcn_mfma_f32_16x16x32_bf16(
                afrag[0], bfp[t][nt], acc[0][nt], 0, 0, 0);
            acc[1][nt] = __builtin_amdgcn_mfma_f32_16x16x32_bf16(
                afrag[1], bfp[t][nt], acc[1][nt], 0, 0, 0);
        }
        accl[0] = __builtin_amdgcn_mfma_f32_16x16x32_bf16(afrag[0], ones, accl[0], 0, 0, 0);
        accl[1] = __builtin_amdgcn_mfma_f32_16x16x32_bf16(afrag[1], ones, accl[1], 0, 0, 0);
        __builtin_amdgcn_s_setprio(0);
        if (ks < 6) LOADTILE(t, ks + 2);
    }

    // ---- epilogue: flat LDS partials, one barrier, 16-way reduce ----
    float* red_w = redbuf + w * 2048;
#pragma unroll
    for (int g = 0; g < 2; ++g) {
        // accl C-layout: row = quad*4+reg, col = lane&15 (all cols equal)
        if (col == 0) {
#pragma unroll
            for (int reg = 0; reg < 4; ++reg)
                lred[w][g * 16 + quad * 4 + reg] = accl[g][reg];
        }
#pragma unroll
        for (int nt = 0; nt < 4; ++nt)
#pragma unroll
            for (int reg = 0; reg < 4; ++reg)
                red_w[g * 1024 + ((nt * 4 + reg) << 6) + lane] = acc[g][nt][reg];
    }
    __syncthreads();

    // 2048 outputs per block (32 rows x 64 f), 1024 threads -> 2 each.
#pragma unroll
    for (int e = 0; e < 2; ++e) {
        int flat = e * 1024 + tid;                // r32*64 + f
        int f    = flat & 63;
        int r32  = flat >> 6;                     // 0..31
        int g    = r32 >> 4;
        int r16  = r32 & 15;
        int q2   = r16 >> 2, reg = r16 & 3;
        int c2   = f & 15,   nt  = f >> 4;
        int ln   = q2 * 16 + c2;
        int off  = g * 1024 + ((nt * 4 + reg) << 6) + ln;
        float acv = 0.f, l = 0.f;
#pragma unroll
        for (int ww = 0; ww < 16; ++ww) {
            acv += redbuf[ww * 2048 + off];
            l   += lred[ww][g * 16 + r16];
        }
        float v = acv / l;
        out[((size_t)(b * NN + i0 + r32) << 6) + f] = v > 0.f ? v : (__expf(v) - 1.f);
    }
}

extern "C" void kernel_launch(void* const* d_in, const int* in_sizes, int n_in,
                              void* d_out, int out_size, void* d_ws, size_t ws_size,
                              hipStream_t stream) {
    const float* h   = (const float*)d_in[0];
    const int*   adj = (const int*)d_in[1];
    const float* W   = (const float*)d_in[2];
    const float* a   = (const float*)d_in[3];
    float* ws  = (float*)d_ws;
    float* out = (float*)d_out;

    hipLaunchKernelGGL(k1_proj, dim3(NB * NN / 4), dim3(256), 0, stream, h, W, a, adj, ws);
    hipLaunchKernelGGL(k3_attn, dim3(256), dim3(1024), 0, stream, ws, out);
}

// Round 10
// 123.091 us; speedup vs baseline: 1.0573x; 1.0573x over previous
//
#include <hip/hip_runtime.h>
#include <hip/hip_bf16.h>
#include <math.h>

#define NB 2
#define NN 4096
#define FIN 128
#define FOUT 64
#define LALPHA 0.2f

// ws float-offsets
#define WS_S1    0                          // NB*NN floats (pre-scaled by log2e)
#define WS_S2    (NB*NN)                    // NB*NN floats (pre-scaled by log2e)
#define WS_WHT   (2*NB*NN)                  // NB*FOUT*NN bf16, tile-major layout
#define WS_ABITS (WS_WHT + NB*FOUT*NN/2)    // NN*(NN/32) uint32 = 2 MiB

// whT tile-major layout: element (b, f, j) lives at
//   (b*(NN/32) + (j>>5)) * 2048 + f*32 + (j&31)

typedef __attribute__((ext_vector_type(8))) short short8;
typedef __attribute__((ext_vector_type(4))) float f32x4;

static __device__ inline unsigned int pack2bf(float x, float y) {
    float2 f2; f2.x = x; f2.y = y;
    __hip_bfloat162 pp = __float22bfloat162_rn(f2);
    return *reinterpret_cast<unsigned int*>(&pp);
}

// native hardware exp2: v_exp_f32 (libm exp2f carries range-fixup overhead;
// our inputs are bounded |e| < ~60 so the fixup path is dead weight)
static __device__ inline float fast_exp2(float x) {
    float r;
    asm("v_exp_f32 %0, %1" : "=v"(r) : "v"(x));
    return r;
}

// async global->LDS, 16B per lane, dst = wave-uniform base + lane*16,
// src = per-lane global address (supplies the permutation)
#define GLL16(gsrc, ldst)                                                        \
    __builtin_amdgcn_global_load_lds(                                            \
        (const __attribute__((address_space(1))) void*)(gsrc),                   \
        (__attribute__((address_space(3))) void*)(ldst), 16, 0, 0)

// K1: Wh = h@W ; s1 = log2e*(Wh@a1) ; s2 = log2e*(Wh@a2) ; WhT bf16 tile-major.
// At its HBM roofline (~8 us, 64 MiB adj stream) — do not touch.
__global__ __launch_bounds__(256) void k1_proj(const float* __restrict__ h,
                                               const float* __restrict__ W,
                                               const float* __restrict__ a,
                                               const int* __restrict__ adj,
                                               float* __restrict__ ws) {
    __shared__ __align__(16) float hbuf[4][128];
    __shared__ float tbuf[4][68];
    int gid  = blockIdx.x * 256 + threadIdx.x;
    int wid  = gid >> 6;            // 0 .. NB*NN-1
    int lane = threadIdx.x & 63;
    int w    = threadIdx.x >> 6;

    // ---- adj pack: coalesced loads issued early ----
    int prow = 2 * blockIdx.x + (w >> 1);
    const int4* psrc = (const int4*)(adj + (size_t)prow * NN + (w & 1) * 2048);
    int4 pv[8];
#pragma unroll
    for (int k = 0; k < 8; ++k) pv[k] = psrc[k * 64 + lane];

    // ---- stage h row (wave-private), then broadcast-read f32x4 ----
    const float* hrow = h + (size_t)wid * FIN;
    hbuf[w][lane]      = hrow[lane];
    hbuf[w][64 + lane] = hrow[64 + lane];

    float acc = 0.f;
#pragma unroll
    for (int f4 = 0; f4 < 32; ++f4) {
        float4 hv = *(const float4*)&hbuf[w][f4 * 4];
        acc = fmaf(hv.x, W[(f4 * 4 + 0) * FOUT + lane], acc);
        acc = fmaf(hv.y, W[(f4 * 4 + 1) * FOUT + lane], acc);
        acc = fmaf(hv.z, W[(f4 * 4 + 2) * FOUT + lane], acc);
        acc = fmaf(hv.w, W[(f4 * 4 + 3) * FOUT + lane], acc);
    }
    tbuf[w][lane] = acc;
    float v1 = acc * a[lane];
    float v2 = acc * a[FOUT + lane];
#pragma unroll
    for (int off = 32; off; off >>= 1) {
        v1 += __shfl_xor(v1, off);
        v2 += __shfl_xor(v2, off);
    }
    if (lane == 0) {
        ws[WS_S1 + wid] = v1 * 1.44269504088896f;   // pre-scale for exp2 in k3
        ws[WS_S2 + wid] = v2 * 1.44269504088896f;
    }

    // ---- finish adj pack: nibble -> word via 3x shfl_xor OR ----
    unsigned int* ab = (unsigned int*)(ws + WS_ABITS);
#pragma unroll
    for (int k = 0; k < 8; ++k) {
        unsigned int nib = (pv[k].x != 0 ? 1u : 0u)
                         | (pv[k].y != 0 ? 2u : 0u)
                         | (pv[k].z != 0 ? 4u : 0u)
                         | (pv[k].w != 0 ? 8u : 0u);
        unsigned int val = nib << ((lane & 7) * 4);
        val |= __shfl_xor(val, 1);
        val |= __shfl_xor(val, 2);
        val |= __shfl_xor(val, 4);
        if ((lane & 7) == 0)
            ab[(size_t)prow * 128 + (w & 1) * 64 + k * 8 + (lane >> 3)] = val;
    }

    __syncthreads();
    // transpose 4 rows x 64 f -> tile-major whT
    if (threadIdx.x < 64) {
        int f = threadIdx.x;
        int wid0 = blockIdx.x * 4;
        int b  = wid0 >> 12;         // wid0 / NN
        int n0 = wid0 & (NN - 1);
        unsigned short* whT = (unsigned short*)(ws + WS_WHT);
        uint2 pk;
        pk.x = pack2bf(tbuf[0][f], tbuf[1][f]);
        pk.y = pack2bf(tbuf[2][f], tbuf[3][f]);
        size_t off = ((size_t)(b * 128 + (n0 >> 5)) * 2048) + f * 32 + (n0 & 31);
        *(uint2*)&whT[off] = pk;
    }
}

// K3: fused masked softmax + P@Wh via MFMA + flat in-block reduction + ELU.
// r8 structure (best measured): GLL-staged tiles, counted vmcnt(4), s2 in LDS,
// ones-MFMA denominator. This round: native v_exp_f32 (was libm exp2f) and a
// 68-float-stride epilogue layout (breaks the 4-way read bank conflict; 2-way
// aliasing is free). LDS: redbuf 136K + s2 16K + lred 2K = 154K, 1 block/CU.
__global__ __launch_bounds__(1024, 4) void k3_attn(const float* __restrict__ ws,
                                                   float* __restrict__ out) {
    __shared__ float redbuf[16 * 2176];   // per-wave: GLL staging (2048f), then 32x68 partials
    __shared__ float s2buf[16][256];      // 16 KiB: per-wave s2 slice
    __shared__ float lred[16][32];        // 2 KiB: l partials (g*16+row)
    const int tid  = threadIdx.x;
    const int w    = tid >> 6;                   // wave id = j-chunk 0..15
    const int lane = tid & 63;
    const int col  = lane & 15;
    const int quad = lane >> 4;
    const int rt   = blockIdx.x & 127;           // 32-row tile 0..127
    const int b    = blockIdx.x >> 7;            // batch
    const int i0   = rt * 32;
    const int jbase = w * 256;

    const float* __restrict__ s1 = ws + WS_S1 + b * NN;
    const float* __restrict__ s2 = ws + WS_S2 + b * NN;
    const unsigned short* __restrict__ whT =
        (const unsigned short*)(ws + WS_WHT) + (size_t)b * FOUT * NN;
    const unsigned int* __restrict__ abits = (const unsigned int*)(ws + WS_ABITS);

    char* slot = (char*)(redbuf + w * 2176);          // wave-private: 2 x 4KB bufs
    float* s2s = s2buf[w];
    const unsigned short* wsrc = whT + (size_t)w * 8 * 2048;  // tile (w*8+ks) @ +ks*2048
    const int lsrc = col * 32 + quad * 8;             // per-lane src perm (shorts)

    // ---- prologue: masks + s1a (VMEM regs), then full drain ----
    unsigned int mrow[2][8];
#pragma unroll
    for (int g = 0; g < 2; ++g) {
        const int4* mp = (const int4*)&abits[(size_t)(i0 + g * 16 + col) * 128 + w * 8];
        *(int4*)&mrow[g][0] = mp[0];
        *(int4*)&mrow[g][4] = mp[1];
    }
    float s1a[2];
#pragma unroll
    for (int g = 0; g < 2; ++g) s1a[g] = s1[i0 + g * 16 + col];
    asm volatile("s_waitcnt vmcnt(0)" ::: "memory");

#define ISSUE_TILE(ks, sl)                                                \
    do {                                                                  \
        const unsigned short* wb_ = wsrc + (size_t)(ks) * 2048;           \
        GLL16(wb_ + 0 * 512 + lsrc, slot + (sl) * 4096 + 0 * 1024);       \
        GLL16(wb_ + 1 * 512 + lsrc, slot + (sl) * 4096 + 1 * 1024);       \
        GLL16(wb_ + 2 * 512 + lsrc, slot + (sl) * 4096 + 2 * 1024);       \
        GLL16(wb_ + 3 * 512 + lsrc, slot + (sl) * 4096 + 3 * 1024);       \
    } while (0)

    // issue order: s2 slice (1 gll), tile0 (4), tile1 (4) -> 9 outstanding
    GLL16(&s2[jbase] + lane * 4, s2s);
    ISSUE_TILE(0, 0);
    ISSUE_TILE(1, 1);
    asm volatile("s_waitcnt vmcnt(8)" ::: "memory");   // s2 slice landed

    // all-ones bf16 B-fragment for denominator row-sum MFMA
    unsigned int onew[4] = {0x3F803F80u, 0x3F803F80u, 0x3F803F80u, 0x3F803F80u};
    const short8 ones = *(short8*)onew;

    f32x4 acc[2][4];          // [group][nt] numerator
    f32x4 accl[2];            // [group] denominator row-sums
#pragma unroll
    for (int g = 0; g < 2; ++g) {
        accl[g] = (f32x4)0.f;
#pragma unroll
        for (int nt = 0; nt < 4; ++nt) acc[g][nt] = (f32x4)0.f;
    }

#pragma unroll
    for (int ks = 0; ks < 8; ++ks) {
        const int sl = ks & 1;

        // ---- p/exp chain from LDS s2 — runs while tile(ks) is in flight ----
        float4 s2lo = *(const float4*)&s2s[ks * 32 + quad * 8];
        float4 s2hi = *(const float4*)&s2s[ks * 32 + quad * 8 + 4];
        float sj[8] = {s2lo.x, s2lo.y, s2lo.z, s2lo.w,
                       s2hi.x, s2hi.y, s2hi.z, s2hi.w};
        short8 afrag[2];
#pragma unroll
        for (int g = 0; g < 2; ++g) {
            const unsigned int mb = (mrow[g][ks] >> (quad * 8)) & 0xffu;
            float p[8];
#pragma unroll
            for (int jj = 0; jj < 8; ++jj) {
                float e = s1a[g] + sj[jj];
                e = fmaxf(e, LALPHA * e);              // leakyrelu
                float pe = fast_exp2(e);               // native v_exp_f32
                p[jj] = ((mb >> jj) & 1u) ? pe : 0.f;  // mask
            }
            unsigned int pk[4];
#pragma unroll
            for (int q = 0; q < 4; ++q) pk[q] = pack2bf(p[2 * q], p[2 * q + 1]);
            afrag[g] = *(short8*)pk;
        }

        // pin the exp chain BEFORE the wait (rule #18), then wait for tile(ks)
        __builtin_amdgcn_sched_barrier(0);
        if (ks == 7) asm volatile("s_waitcnt vmcnt(0)" ::: "memory");
        else         asm volatile("s_waitcnt vmcnt(4)" ::: "memory");

        __builtin_amdgcn_s_setprio(1);
#pragma unroll
        for (int nt = 0; nt < 4; ++nt) {
            short8 bf = *(const short8*)(slot + sl * 4096 + nt * 1024 + lane * 16);
            acc[0][nt] = __builtin_amdgcn_mfma_f32_16x16x32_bf16(
                afrag[0], bf, acc[0][nt], 0, 0, 0);
            acc[1][nt] = __builtin_amdgcn_mfma_f32_16x16x32_bf16(
                afrag[1], bf, acc[1][nt], 0, 0, 0);
        }
        accl[0] = __builtin_amdgcn_mfma_f32_16x16x32_bf16(afrag[0], ones, accl[0], 0, 0, 0);
        accl[1] = __builtin_amdgcn_mfma_f32_16x16x32_bf16(afrag[1], ones, accl[1], 0, 0, 0);
        __builtin_amdgcn_s_setprio(0);
        if (ks < 6) ISSUE_TILE(ks + 2, sl);
    }

    // ---- epilogue: padded LDS partials (68-stride rows), one barrier ----
    float* red_w = redbuf + w * 2176;
#pragma unroll
    for (int g = 0; g < 2; ++g) {
        // accl C-layout: row = quad*4+reg, col = lane&15 (all cols equal)
        if (col == 0) {
#pragma unroll
            for (int reg = 0; reg < 4; ++reg)
                lred[w][g * 16 + quad * 4 + reg] = accl[g][reg];
        }
#pragma unroll
        for (int nt = 0; nt < 4; ++nt)
#pragma unroll
            for (int reg = 0; reg < 4; ++reg)
                red_w[(g * 16 + nt * 4 + reg) * 68 + lane] = acc[g][nt][reg];
    }
    __syncthreads();

    // 2048 outputs per block (32 rows x 64 f), 1024 threads -> 2 each.
#pragma unroll
    for (int e = 0; e < 2; ++e) {
        int flat = e * 1024 + tid;                // r32*64 + f
        int f    = flat & 63;
        int r32  = flat >> 6;                     // 0..31
        int g    = r32 >> 4;
        int r16  = r32 & 15;
        int q2   = r16 >> 2, reg = r16 & 3;
        int c2   = f & 15,   nt  = f >> 4;
        int ln   = q2 * 16 + c2;
        int off  = (g * 16 + nt * 4 + reg) * 68 + ln;
        float acv = 0.f, l = 0.f;
#pragma unroll
        for (int ww = 0; ww < 16; ++ww) {
            acv += redbuf[ww * 2176 + off];
            l   += lred[ww][g * 16 + r16];
        }
        float v = acv / l;
        out[((size_t)(b * NN + i0 + r32) << 6) + f] = v > 0.f ? v : (__expf(v) - 1.f);
    }
}

extern "C" void kernel_launch(void* const* d_in, const int* in_sizes, int n_in,
                              void* d_out, int out_size, void* d_ws, size_t ws_size,
                              hipStream_t stream) {
    const float* h   = (const float*)d_in[0];
    const int*   adj = (const int*)d_in[1];
    const float* W   = (const float*)d_in[2];
    const float* a   = (const float*)d_in[3];
    float* ws  = (float*)d_ws;
    float* out = (float*)d_out;

    hipLaunchKernelGGL(k1_proj, dim3(NB * NN / 4), dim3(256), 0, stream, h, W, a, adj, ws);
    hipLaunchKernelGGL(k3_attn, dim3(256), dim3(1024), 0, stream, ws, out);
}